// Round 4
// baseline (1361.344 us; speedup 1.0000x reference)
//
#include <hip/hip_runtime.h>
#include <math.h>

// AAModel round 4: wave-owns-output-group conv. Each wave computes a disjoint
// set of TP outputs to completion in registers (no partial-sum pool, no
// cross-wave reduce), scattering via native f32 atomics. Transposed fp32
// operand tables in LDS give b128 epilogue reads. LDS ~40KB -> 4 blocks/CU.

constexpr float SQ3f = 1.7320508075688772f;
constexpr float INV1 = 0.14433756729740643f;  // 1/sqrt(48)
constexpr float NAc  = 0.10206207261596575f;  // 1/sqrt(2*48)
constexpr float NBc  = 0.22360679774997896f;  // 1/sqrt(2*10)
constexpr float C20  = 0.22360679774997896f;  // 1/sqrt(20)
constexpr float RATIO= 1.2649110640673518f;   // (NBc/sqrt3)/NAc
constexpr float DSP  = 30.0f/31.0f;
constexpr float GCOEF= -0.5f/(DSP*DSP);

typedef __attribute__((ext_vector_type(8))) short bf16x8;
typedef __attribute__((ext_vector_type(4))) float f32x4;

__device__ __forceinline__ unsigned short f2bf(float x) {
    unsigned u = __builtin_bit_cast(unsigned, x);
    u += 0x7fffu + ((u >> 16) & 1u);     // RNE
    return (unsigned short)(u >> 16);
}

// tile/lane-slot -> original W2 column (or -1 = padding lane)
__device__ __forceinline__ int colmap(int layer, int t, int lm) {
    if (layer == 0) return t*16 + lm;                           // W1 identity
    if (layer == 1) {
        if (t < 144) { const int og=t/48, i=t-og*48; return i*48 + og*16 + lm; }      // w00
        const int i = t-144; return (lm<10) ? 2304 + i*10 + lm : -1;                  // w01
    }
    if (t < 144) { const int og=t/48, i=t-og*48; return i*48 + og*16 + lm; }          // w00
    if (t < 174) { const int s=t-144, og=s/10, i=s-og*10; return 2884 + i*48 + og*16 + lm; } // w11s
    if (t < 222) { const int i=t-174; return (lm<10) ? 2304 + i*10 + lm : -1; }       // w01
    if (t < 232) { const int i=t-222; return (lm<10) ? 2784 + i*10 + lm : -1; }       // w10
    { const int i=t-232; return (lm<10) ? 3364 + i*10 + lm : -1; }                    // w11p
}

__global__ __launch_bounds__(256)
void cvt_swz(const float* __restrict__ W, const float* __restrict__ bias,
             short* __restrict__ Wsw, int ncol, int ntile, int layer)
{
    const int gid = blockIdx.x*256 + threadIdx.x;
    const int g = gid >> 6, lane = gid & 63;
    if (g >= ntile*5) return;
    const int tile = g/5, ks = g - tile*5;
    const int c  = colmap(layer, tile, lane & 15);
    const int k0 = ks*32 + (lane >> 4)*8;
    union { uint4 u4; unsigned short h[8]; } pk;
    #pragma unroll
    for (int j=0;j<8;j++) {
        const int k = k0 + j;
        float v = 0.f;
        if (c >= 0) {
            if (k < 144)       v = W[(size_t)k*ncol + c];
            else if (k == 144) v = bias[c];
        }
        pk.h[j] = f2bf(v);
    }
    *(uint4*)&Wsw[((size_t)g*64 + lane)*8] = pk.u4;
}

// ----------------------------------------------------------------------------
__global__ __launch_bounds__(256)
void edge_kernel(const float* __restrict__ pos, const float* __restrict__ sigma,
                 const int* __restrict__ ei,
                 const float* __restrict__ W1, const float* __restrict__ b1,
                 const float* __restrict__ W2, const float* __restrict__ b2,
                 float* __restrict__ edge_emb, float* __restrict__ sh1buf,
                 int* __restrict__ deg, int E)
{
    __shared__ float inl[4][64];
    __shared__ float hidl[4][48];
    const int w    = threadIdx.x >> 6;
    const int lane = threadIdx.x & 63;
    const int e    = blockIdx.x*4 + w;
    const bool valid = (e < E);
    const int ec = valid ? e : 0;
    const int src = ei[ec], dst = ei[E+ec];
    const float vx = pos[dst*3+0]-pos[src*3+0];
    const float vy = pos[dst*3+1]-pos[src*3+1];
    const float vz = pos[dst*3+2]-pos[src*3+2];
    const float d  = sqrtf(vx*vx+vy*vy+vz*vz);
    const float si = SQ3f/(d+1e-8f);
    const float s0 = vx*si, s1 = vy*si, s2 = vz*si;
    if (lane < 32) {
        inl[w][lane] = sigma[src*32+lane];
    } else {
        const float off  = (float)(lane-32)*DSP;
        const float diff = d - off;
        inl[w][lane] = expf(GCOEF*diff*diff);
    }
    __syncthreads();
    if (lane < 48) {
        float a = b1[lane];
        #pragma unroll 8
        for (int j=0;j<64;j++) a = fmaf(inl[w][j], W1[j*48+lane], a);
        hidl[w][lane] = fmaxf(a, 0.f);
    }
    __syncthreads();
    if (valid) {
        if (lane < 48) {
            float a = b2[lane];
            #pragma unroll 8
            for (int j=0;j<48;j++) a = fmaf(hidl[w][j], W2[j*48+lane], a);
            edge_emb[e*48+lane] = a;
        }
        if (lane == 0) atomicAdd(&deg[dst], 1);
        if (lane < 3)  sh1buf[e*4+lane] = (lane==0)?s0:((lane==1)?s1:s2);
    }
}

// ----------------------------------------------------------------------------
__device__ __forceinline__ void load_bfrag(const short* __restrict__ Wsw,
                                           int tile, int lane, bf16x8 (&b)[5]) {
    #pragma unroll
    for (int ks=0; ks<5; ks++)
        b[ks] = *(const bf16x8*)&Wsw[((size_t)(tile*5+ks)*64 + lane)*8];
}

__device__ __forceinline__ void mfma5(const bf16x8 (&ag)[2][5], const bf16x8 (&b)[5],
                                      f32x4& a0, f32x4& a1) {
    a0 = (f32x4){0.f,0.f,0.f,0.f};
    a1 = (f32x4){0.f,0.f,0.f,0.f};
    #pragma unroll
    for (int ks=0; ks<5; ks++) {
        a0 = __builtin_amdgcn_mfma_f32_16x16x32_bf16(ag[0][ks], b[ks], a0, 0,0,0);
        a1 = __builtin_amdgcn_mfma_f32_16x16x32_bf16(ag[1][ks], b[ks], a1, 0,0,0);
    }
}

// ----------------------------------------------------------------------------
template<int LAYER>
__global__ __launch_bounds__(256, 4)
void conv_kernel(const float* __restrict__ edge_emb, const float* __restrict__ sh1buf,
                 const int* __restrict__ ei,
                 const float* __restrict__ sin_, const float* __restrict__ vin,
                 const short* __restrict__ W1sw, const short* __restrict__ W2sw,
                 float* __restrict__ outS, float* __restrict__ outV, int E)
{
    __shared__ __align__(16) short eaB[32*192];
    __shared__ __align__(16) short hidB[32*192];
    __shared__ __align__(16) float xsT[48][32];   // xs transposed: [chan][edge]
    __shared__ float sh1l[32][4];
    __shared__ int   srcl[32], dstl[32];
    __shared__ __align__(16) float xvT[LAYER==2 ? 30 : 1][32];
    __shared__ __align__(16) float uT [LAYER==2 ? 10 : 1][32];
    __shared__ __align__(16) float cvT[LAYER==2 ? 30 : 1][32];

    const int t  = threadIdx.x;
    const int eb = blockIdx.x * 32;

    if (t < 32) {
        const int ge = eb + t; const int gc = (ge < E) ? ge : (E-1);
        srcl[t] = ei[gc]; dstl[t] = ei[E+gc];
    }
    if (t < 128) {
        const int e = t >> 2, k = t & 3;
        const int ge = eb + e; const int gc = (ge<E)?ge:(E-1);
        sh1l[e][k] = sh1buf[gc*4 + k];
    }
    __syncthreads();

    // ---- stage ea -> bf16 swizzled LDS
    for (int p = t; p < 32*24; p += 256) {
        const int m = p / 24, s = p - m*24;
        const int k0 = s*8;
        float vals[8] = {0.f,0.f,0.f,0.f,0.f,0.f,0.f,0.f};
        if (k0 < 48) {
            const int ge = eb + m; const int gc = (ge<E)?ge:(E-1);
            const float4 a = *(const float4*)&edge_emb[gc*48 + k0];
            const float4 b = *(const float4*)&edge_emb[gc*48 + k0 + 4];
            vals[0]=a.x; vals[1]=a.y; vals[2]=a.z; vals[3]=a.w;
            vals[4]=b.x; vals[5]=b.y; vals[6]=b.z; vals[7]=b.w;
        } else if (k0 < 96) {
            const float4 a = *(const float4*)&sin_[srcl[m]*48 + (k0-48)];
            const float4 b = *(const float4*)&sin_[srcl[m]*48 + (k0-48) + 4];
            vals[0]=a.x; vals[1]=a.y; vals[2]=a.z; vals[3]=a.w;
            vals[4]=b.x; vals[5]=b.y; vals[6]=b.z; vals[7]=b.w;
        } else if (k0 < 144) {
            const float4 a = *(const float4*)&sin_[dstl[m]*48 + (k0-96)];
            const float4 b = *(const float4*)&sin_[dstl[m]*48 + (k0-96) + 4];
            vals[0]=a.x; vals[1]=a.y; vals[2]=a.z; vals[3]=a.w;
            vals[4]=b.x; vals[5]=b.y; vals[6]=b.z; vals[7]=b.w;
        } else if (k0 == 144) {
            vals[0] = 1.f;                       // bias row
        }
        union { uint4 u4; unsigned short h[8]; } pk;
        #pragma unroll
        for (int j=0;j<8;j++) pk.h[j] = f2bf(vals[j]);
        *(uint4*)&eaB[m*192 + ((s ^ (m&7))*8)] = pk.u4;
    }
    // hidB K-pad: k=144 -> 1.0 (bias row), 145..159 -> 0
    if (t < 64) {
        const int m = t >> 1, s = 18 + (t & 1);
        union { uint4 u4; unsigned short h[8]; } pk;
        pk.u4.x = pk.u4.y = pk.u4.z = pk.u4.w = 0u;
        if (s == 18) pk.h[0] = f2bf(1.f);
        *(uint4*)&hidB[m*192 + ((s ^ (m&7))*8)] = pk.u4;
    }
    // xsT: fp32 transposed gather (L2-hot; conflict-free LDS writes)
    for (int p=t; p<1536; p+=256) {
        const int k = p >> 5, e = p & 31;
        xsT[k][e] = sin_[srcl[e]*48 + k];
    }
    if (LAYER==2) {
        for (int p=t; p<320; p+=256) {
            const int i = p >> 5, e = p & 31;
            const float x0 = vin[srcl[e]*30 + i*3+0];
            const float x1 = vin[srcl[e]*30 + i*3+1];
            const float x2 = vin[srcl[e]*30 + i*3+2];
            const float h0=sh1l[e][0], h1=sh1l[e][1], h2=sh1l[e][2];
            xvT[i*3+0][e]=x0; xvT[i*3+1][e]=x1; xvT[i*3+2][e]=x2;
            uT[i][e] = x0*h0 + x1*h1 + x2*h2;
            cvT[i*3+0][e] = x1*h2 - x2*h1;
            cvT[i*3+1][e] = x2*h0 - x0*h2;
            cvT[i*3+2][e] = x0*h1 - x1*h0;
        }
    }
    __syncthreads();

    const int wv = t >> 6, lane = t & 63;
    const int lm = lane & 15, lk = lane >> 4, lk4 = lk*4;

    // ---- GEMM1: hid = relu(ea @ W1) -> swizzled bf16 LDS
    {
        bf16x8 af[2][5];
        #pragma unroll
        for (int mt=0; mt<2; mt++) {
            const int m = mt*16 + lm;
            #pragma unroll
            for (int ks=0; ks<5; ks++)
                af[mt][ks] = *(const bf16x8*)&eaB[m*192 + (((ks*4+lk) ^ (m&7))*8)];
        }
        for (int nt = wv; nt < 9; nt += 4) {
            bf16x8 bw[5];
            load_bfrag(W1sw, nt, lane, bw);
            f32x4 a0, a1;
            mfma5(af, bw, a0, a1);
            const int c = nt*16 + lm;
            #pragma unroll
            for (int r=0; r<4; r++) {
                const int m0 = lk4 + r, m1 = 16 + lk4 + r;
                hidB[m0*192 + (((c>>3) ^ (m0&7))*8) + (c&7)] = (short)f2bf(fmaxf(a0[r], 0.f));
                hidB[m1*192 + (((c>>3) ^ (m1&7))*8) + (c&7)] = (short)f2bf(fmaxf(a1[r], 0.f));
            }
        }
    }
    __syncthreads();

    bf16x8 ag[2][5];
    #pragma unroll
    for (int mt=0; mt<2; mt++) {
        const int m = mt*16 + lm;
        #pragma unroll
        for (int ks=0; ks<5; ks++)
            ag[mt][ks] = *(const bf16x8*)&hidB[m*192 + (((ks*4+lk) ^ (m&7))*8)];
    }

    if (wv < 3) {
        // ---- this wave owns w00 output group og=wv (full i-sum in registers)
        float ms[2][4] = {{0.f,0.f,0.f,0.f},{0.f,0.f,0.f,0.f}};
        {
            bf16x8 b0[5], b1_[5];
            const int base = wv*48;
            load_bfrag(W2sw, base, lane, b0);
            for (int i=0; i<48; i+=2) {
                load_bfrag(W2sw, base+i+1, lane, b1_);
                f32x4 a0, a1;
                mfma5(ag, b0, a0, a1);
                {
                    const f32x4 x0 = *(const f32x4*)&xsT[i][lk4];
                    const f32x4 x1 = *(const f32x4*)&xsT[i][16+lk4];
                    #pragma unroll
                    for (int r=0;r<4;r++) {
                        ms[0][r] = fmaf(a0[r], x0[r], ms[0][r]);
                        ms[1][r] = fmaf(a1[r], x1[r], ms[1][r]);
                    }
                }
                if (i+2 < 48) load_bfrag(W2sw, base+i+2, lane, b0);
                mfma5(ag, b1_, a0, a1);
                {
                    const f32x4 x0 = *(const f32x4*)&xsT[i+1][lk4];
                    const f32x4 x1 = *(const f32x4*)&xsT[i+1][16+lk4];
                    #pragma unroll
                    for (int r=0;r<4;r++) {
                        ms[0][r] = fmaf(a0[r], x0[r], ms[0][r]);
                        ms[1][r] = fmaf(a1[r], x1[r], ms[1][r]);
                    }
                }
            }
        }
        if (LAYER==2) {
            // + w11s og=wv (10 tiles, uT, factor RATIO)
            bf16x8 b0[5], b1_[5];
            const int base = 144 + wv*10;
            load_bfrag(W2sw, base, lane, b0);
            for (int i=0; i<10; i+=2) {
                load_bfrag(W2sw, base+i+1, lane, b1_);
                f32x4 a0, a1;
                mfma5(ag, b0, a0, a1);
                {
                    const f32x4 u0 = *(const f32x4*)&uT[i][lk4];
                    const f32x4 u1 = *(const f32x4*)&uT[i][16+lk4];
                    #pragma unroll
                    for (int r=0;r<4;r++) {
                        ms[0][r] = fmaf(a0[r]*RATIO, u0[r], ms[0][r]);
                        ms[1][r] = fmaf(a1[r]*RATIO, u1[r], ms[1][r]);
                    }
                }
                if (i+2 < 10) load_bfrag(W2sw, base+i+2, lane, b0);
                mfma5(ag, b1_, a0, a1);
                {
                    const f32x4 u0 = *(const f32x4*)&uT[i+1][lk4];
                    const f32x4 u1 = *(const f32x4*)&uT[i+1][16+lk4];
                    #pragma unroll
                    for (int r=0;r<4;r++) {
                        ms[0][r] = fmaf(a0[r]*RATIO, u0[r], ms[0][r]);
                        ms[1][r] = fmaf(a1[r]*RATIO, u1[r], ms[1][r]);
                    }
                }
            }
        }
        // scatter
        const float scale = (LAYER==1) ? INV1 : NAc;
        const int   strd  = (LAYER==1) ? 48 : 108;
        const int o = wv*16 + lm;
        #pragma unroll
        for (int r=0;r<4;r++) {
            const int e0 = lk4+r, e1 = 16+lk4+r;
            if (eb+e0 < E) unsafeAtomicAdd(&outS[(size_t)dstl[e0]*strd + o], ms[0][r]*scale);
            if (eb+e1 < E) unsafeAtomicAdd(&outS[(size_t)dstl[e1]*strd + o], ms[1][r]*scale);
        }
    } else {
        // ---- wave 3 owns the vector-channel outputs
        float vc[2][4] = {{0.f,0.f,0.f,0.f},{0.f,0.f,0.f,0.f}};
        {
            bf16x8 b0[5], b1_[5];
            const int base = (LAYER==1) ? 144 : 174;   // w01
            load_bfrag(W2sw, base, lane, b0);
            for (int i=0; i<48; i+=2) {
                load_bfrag(W2sw, base+i+1, lane, b1_);
                f32x4 a0, a1;
                mfma5(ag, b0, a0, a1);
                {
                    const f32x4 x0 = *(const f32x4*)&xsT[i][lk4];
                    const f32x4 x1 = *(const f32x4*)&xsT[i][16+lk4];
                    #pragma unroll
                    for (int r=0;r<4;r++) {
                        vc[0][r] = fmaf(a0[r], x0[r], vc[0][r]);
                        vc[1][r] = fmaf(a1[r], x1[r], vc[1][r]);
                    }
                }
                if (i+2 < 48) load_bfrag(W2sw, base+i+2, lane, b0);
                mfma5(ag, b1_, a0, a1);
                {
                    const f32x4 x0 = *(const f32x4*)&xsT[i+1][lk4];
                    const f32x4 x1 = *(const f32x4*)&xsT[i+1][16+lk4];
                    #pragma unroll
                    for (int r=0;r<4;r++) {
                        vc[0][r] = fmaf(a0[r], x0[r], vc[0][r]);
                        vc[1][r] = fmaf(a1[r], x1[r], vc[1][r]);
                    }
                }
            }
        }
        if (LAYER==1) {
            if (lm < 10) {
                #pragma unroll
                for (int r=0;r<4;r++) {
                    const int e0 = lk4+r, e1 = 16+lk4+r;
                    const float v0 = vc[0][r]*INV1, v1 = vc[1][r]*INV1;
                    #pragma unroll
                    for (int d=0; d<3; d++) {
                        if (eb+e0 < E) unsafeAtomicAdd(&outV[(size_t)dstl[e0]*30 + lm*3 + d], v0*sh1l[e0][d]);
                        if (eb+e1 < E) unsafeAtomicAdd(&outV[(size_t)dstl[e1]*30 + lm*3 + d], v1*sh1l[e1][d]);
                    }
                }
            }
        } else {
            float m3[2][4][3] = {};
            {   // w10: tiles 222..232, xvT
                bf16x8 b0[5], b1_[5];
                load_bfrag(W2sw, 222, lane, b0);
                for (int i=0; i<10; i+=2) {
                    load_bfrag(W2sw, 222+i+1, lane, b1_);
                    f32x4 a0, a1;
                    mfma5(ag, b0, a0, a1);
                    #pragma unroll
                    for (int d=0; d<3; d++) {
                        const f32x4 x0 = *(const f32x4*)&xvT[i*3+d][lk4];
                        const f32x4 x1 = *(const f32x4*)&xvT[i*3+d][16+lk4];
                        #pragma unroll
                        for (int r=0;r<4;r++) {
                            m3[0][r][d] = fmaf(a0[r], x0[r], m3[0][r][d]);
                            m3[1][r][d] = fmaf(a1[r], x1[r], m3[1][r][d]);
                        }
                    }
                    if (i+2 < 10) load_bfrag(W2sw, 222+i+2, lane, b0);
                    mfma5(ag, b1_, a0, a1);
                    #pragma unroll
                    for (int d=0; d<3; d++) {
                        const f32x4 x0 = *(const f32x4*)&xvT[(i+1)*3+d][lk4];
                        const f32x4 x1 = *(const f32x4*)&xvT[(i+1)*3+d][16+lk4];
                        #pragma unroll
                        for (int r=0;r<4;r++) {
                            m3[0][r][d] = fmaf(a0[r], x0[r], m3[0][r][d]);
                            m3[1][r][d] = fmaf(a1[r], x1[r], m3[1][r][d]);
                        }
                    }
                }
            }
            if (lm < 10) {
                #pragma unroll
                for (int r=0;r<4;r++) {
                    const int e0 = lk4+r, e1 = 16+lk4+r;
                    const float v0 = vc[0][r]*NAc, v1 = vc[1][r]*NAc;
                    #pragma unroll
                    for (int d=0; d<3; d++) {
                        if (eb+e0 < E)
                            unsafeAtomicAdd(&outS[(size_t)dstl[e0]*108 + 48 + lm*3 + d],
                                            v0*sh1l[e0][d] + m3[0][r][d]*NBc);
                        if (eb+e1 < E)
                            unsafeAtomicAdd(&outS[(size_t)dstl[e1]*108 + 48 + lm*3 + d],
                                            v1*sh1l[e1][d] + m3[1][r][d]*NBc);
                    }
                }
            }
            // w11p: tiles 232..242, cvT (reuse m3)
            #pragma unroll
            for (int a=0;a<2;a++)
                #pragma unroll
                for (int r=0;r<4;r++)
                    #pragma unroll
                    for (int d=0;d<3;d++) m3[a][r][d] = 0.f;
            {
                bf16x8 b0[5], b1_[5];
                load_bfrag(W2sw, 232, lane, b0);
                for (int i=0; i<10; i+=2) {
                    load_bfrag(W2sw, 232+i+1, lane, b1_);
                    f32x4 a0, a1;
                    mfma5(ag, b0, a0, a1);
                    #pragma unroll
                    for (int d=0; d<3; d++) {
                        const f32x4 x0 = *(const f32x4*)&cvT[i*3+d][lk4];
                        const f32x4 x1 = *(const f32x4*)&cvT[i*3+d][16+lk4];
                        #pragma unroll
                        for (int r=0;r<4;r++) {
                            m3[0][r][d] = fmaf(a0[r], x0[r], m3[0][r][d]);
                            m3[1][r][d] = fmaf(a1[r], x1[r], m3[1][r][d]);
                        }
                    }
                    if (i+2 < 10) load_bfrag(W2sw, 232+i+2, lane, b0);
                    mfma5(ag, b1_, a0, a1);
                    #pragma unroll
                    for (int d=0; d<3; d++) {
                        const f32x4 x0 = *(const f32x4*)&cvT[(i+1)*3+d][lk4];
                        const f32x4 x1 = *(const f32x4*)&cvT[(i+1)*3+d][16+lk4];
                        #pragma unroll
                        for (int r=0;r<4;r++) {
                            m3[0][r][d] = fmaf(a0[r], x0[r], m3[0][r][d]);
                            m3[1][r][d] = fmaf(a1[r], x1[r], m3[1][r][d]);
                        }
                    }
                }
            }
            if (lm < 10) {
                #pragma unroll
                for (int r=0;r<4;r++) {
                    const int e0 = lk4+r, e1 = 16+lk4+r;
                    #pragma unroll
                    for (int d=0; d<3; d++) {
                        if (eb+e0 < E)
                            unsafeAtomicAdd(&outS[(size_t)dstl[e0]*108 + 78 + lm*3 + d], m3[0][r][d]*C20);
                        if (eb+e1 < E)
                            unsafeAtomicAdd(&outS[(size_t)dstl[e1]*108 + 78 + lm*3 + d], m3[1][r][d]*C20);
                    }
                }
            }
        }
    }
}

// ----------------------------------------------------------------------------
__global__ __launch_bounds__(256)
void fin1_kernel(const float* __restrict__ node_s, const int* __restrict__ deg,
                 float* __restrict__ s1, float* __restrict__ v1, int Nn)
{
    const int p = blockIdx.x*256 + threadIdx.x;
    const int totS = Nn*48;
    if (p < totS) {
        const int n = p/48;
        const int dgi = deg[n];
        const float dg = (float)(dgi > 1 ? dgi : 1);
        s1[p] = node_s[p] + s1[p]/dg;
    } else {
        const int q = p - totS;
        if (q < Nn*30) {
            const int n = q/30;
            const int dgi = deg[n];
            const float dg = (float)(dgi > 1 ? dgi : 1);
            v1[q] = v1[q]/dg;
        }
    }
}

__global__ __launch_bounds__(256)
void fin2_kernel(const float* __restrict__ s1, const float* __restrict__ v1,
                 const int* __restrict__ deg, float* __restrict__ out, int Nn)
{
    const int p = blockIdx.x*256 + threadIdx.x;
    if (p >= Nn*108) return;
    const int n = p/108, c = p - n*108;
    const int dgi = deg[n];
    const float dg = (float)(dgi > 1 ? dgi : 1);
    const float acc = out[p]/dg;
    if (c < 48)      out[p] = s1[n*48+c] + acc;
    else if (c < 78) out[p] = v1[n*30 + (c-48)] + acc;
    else             out[p] = acc;
}

// ----------------------------------------------------------------------------
extern "C" void kernel_launch(void* const* d_in, const int* in_sizes, int n_in,
                              void* d_out, int out_size, void* d_ws, size_t ws_size,
                              hipStream_t stream)
{
    const float* pos    = (const float*)d_in[0];
    const float* sigma  = (const float*)d_in[1];
    const float* node_s = (const float*)d_in[2];
    const float* eW1  = (const float*)d_in[3];
    const float* eb1  = (const float*)d_in[4];
    const float* eW2  = (const float*)d_in[5];
    const float* eb2  = (const float*)d_in[6];
    const float* f1W1 = (const float*)d_in[7];
    const float* f1b1 = (const float*)d_in[8];
    const float* f1W2 = (const float*)d_in[9];
    const float* f1b2 = (const float*)d_in[10];
    const float* f2W1 = (const float*)d_in[11];
    const float* f2b1 = (const float*)d_in[12];
    const float* f2W2 = (const float*)d_in[13];
    const float* f2b2 = (const float*)d_in[14];
    const int*   ei   = (const int*)d_in[15];
    const int Nn = in_sizes[0]/3;
    const int E  = in_sizes[15]/2;
    float* out = (float*)d_out;

    char* ws = (char*)d_ws;
    float* edge_emb = (float*)ws;  ws += (size_t)E*48*sizeof(float);
    float* sh1buf   = (float*)ws;  ws += (size_t)E*4*sizeof(float);
    float* s1       = (float*)ws;  ws += (size_t)Nn*48*sizeof(float);
    float* v1       = (float*)ws;  ws += (size_t)Nn*30*sizeof(float);
    int*   deg      = (int*)ws;    ws += (size_t)Nn*sizeof(int);
    short* W1sw     = (short*)ws;  ws += (size_t)9*5*64*8*sizeof(short);
    short* W2sw     = (short*)ws;  ws += (size_t)242*5*64*8*sizeof(short);

    hipMemsetAsync(s1,  0, (size_t)Nn*48*sizeof(float), stream);
    hipMemsetAsync(v1,  0, (size_t)Nn*30*sizeof(float), stream);
    hipMemsetAsync(deg, 0, (size_t)Nn*sizeof(int),      stream);
    hipMemsetAsync(out, 0, (size_t)Nn*108*sizeof(float), stream);

    edge_kernel<<<(E+3)/4, 256, 0, stream>>>(pos, sigma, ei, eW1, eb1, eW2, eb2,
                                             edge_emb, sh1buf, deg, E);

    cvt_swz<<<(9*5*64+255)/256,   256, 0, stream>>>(f1W1, f1b1, W1sw, 144, 9, 0);
    cvt_swz<<<(192*5*64+255)/256, 256, 0, stream>>>(f1W2, f1b2, W2sw, 2784, 192, 1);

    conv_kernel<1><<<(E+31)/32, 256, 0, stream>>>(edge_emb, sh1buf, ei, node_s, nullptr,
                                                  W1sw, W2sw, s1, v1, E);
    fin1_kernel<<<((size_t)Nn*78 + 255)/256, 256, 0, stream>>>(node_s, deg, s1, v1, Nn);

    cvt_swz<<<(9*5*64+255)/256,   256, 0, stream>>>(f2W1, f2b1, W1sw, 144, 9, 0);
    cvt_swz<<<(242*5*64+255)/256, 256, 0, stream>>>(f2W2, f2b2, W2sw, 3464, 242, 2);

    conv_kernel<2><<<(E+31)/32, 256, 0, stream>>>(edge_emb, sh1buf, ei, s1, v1,
                                                  W1sw, W2sw, out, nullptr, E);
    fin2_kernel<<<((size_t)Nn*108 + 255)/256, 256, 0, stream>>>(s1, v1, deg, out, Nn);
}

// Round 5
// 1327.138 us; speedup vs baseline: 1.0258x; 1.0258x over previous
//
#include <hip/hip_runtime.h>
#include <math.h>

// AAModel round 5: round-4 structure (wave-owns-output-group, register-complete
// TP sums, native f32 atomic scatter) with the register budget FIXED:
// __launch_bounds__(256,3) instead of (256,4). Round 4's (256,4) capped VGPR
// at 64 -> scratch spills in the tile loop (FETCH 978MB, WRITE 801MB). The
// kernel needs ~130 VGPR; cap at ~170 guarantees no spill + 3 blocks/CU.
// xsT is now filled from the staging loop's fp32 values (no extra global
// gather); stride-36 rows keep b128 reads aligned and writes bank-spread.

constexpr float SQ3f = 1.7320508075688772f;
constexpr float INV1 = 0.14433756729740643f;  // 1/sqrt(48)
constexpr float NAc  = 0.10206207261596575f;  // 1/sqrt(2*48)
constexpr float NBc  = 0.22360679774997896f;  // 1/sqrt(2*10)
constexpr float C20  = 0.22360679774997896f;  // 1/sqrt(20)
constexpr float RATIO= 1.2649110640673518f;   // (NBc/sqrt3)/NAc
constexpr float DSP  = 30.0f/31.0f;
constexpr float GCOEF= -0.5f/(DSP*DSP);

typedef __attribute__((ext_vector_type(8))) short bf16x8;
typedef __attribute__((ext_vector_type(4))) float f32x4;

__device__ __forceinline__ unsigned short f2bf(float x) {
    unsigned u = __builtin_bit_cast(unsigned, x);
    u += 0x7fffu + ((u >> 16) & 1u);     // RNE
    return (unsigned short)(u >> 16);
}

// tile/lane-slot -> original W2 column (or -1 = padding lane)
__device__ __forceinline__ int colmap(int layer, int t, int lm) {
    if (layer == 0) return t*16 + lm;                           // W1 identity
    if (layer == 1) {
        if (t < 144) { const int og=t/48, i=t-og*48; return i*48 + og*16 + lm; }      // w00
        const int i = t-144; return (lm<10) ? 2304 + i*10 + lm : -1;                  // w01
    }
    if (t < 144) { const int og=t/48, i=t-og*48; return i*48 + og*16 + lm; }          // w00
    if (t < 174) { const int s=t-144, og=s/10, i=s-og*10; return 2884 + i*48 + og*16 + lm; } // w11s
    if (t < 222) { const int i=t-174; return (lm<10) ? 2304 + i*10 + lm : -1; }       // w01
    if (t < 232) { const int i=t-222; return (lm<10) ? 2784 + i*10 + lm : -1; }       // w10
    { const int i=t-232; return (lm<10) ? 3364 + i*10 + lm : -1; }                    // w11p
}

__global__ __launch_bounds__(256)
void cvt_swz(const float* __restrict__ W, const float* __restrict__ bias,
             short* __restrict__ Wsw, int ncol, int ntile, int layer)
{
    const int gid = blockIdx.x*256 + threadIdx.x;
    const int g = gid >> 6, lane = gid & 63;
    if (g >= ntile*5) return;
    const int tile = g/5, ks = g - tile*5;
    const int c  = colmap(layer, tile, lane & 15);
    const int k0 = ks*32 + (lane >> 4)*8;
    union { uint4 u4; unsigned short h[8]; } pk;
    #pragma unroll
    for (int j=0;j<8;j++) {
        const int k = k0 + j;
        float v = 0.f;
        if (c >= 0) {
            if (k < 144)       v = W[(size_t)k*ncol + c];
            else if (k == 144) v = bias[c];
        }
        pk.h[j] = f2bf(v);
    }
    *(uint4*)&Wsw[((size_t)g*64 + lane)*8] = pk.u4;
}

// ----------------------------------------------------------------------------
__global__ __launch_bounds__(256)
void edge_kernel(const float* __restrict__ pos, const float* __restrict__ sigma,
                 const int* __restrict__ ei,
                 const float* __restrict__ W1, const float* __restrict__ b1,
                 const float* __restrict__ W2, const float* __restrict__ b2,
                 float* __restrict__ edge_emb, float* __restrict__ sh1buf,
                 int* __restrict__ deg, int E)
{
    __shared__ float inl[4][64];
    __shared__ float hidl[4][48];
    const int w    = threadIdx.x >> 6;
    const int lane = threadIdx.x & 63;
    const int e    = blockIdx.x*4 + w;
    const bool valid = (e < E);
    const int ec = valid ? e : 0;
    const int src = ei[ec], dst = ei[E+ec];
    const float vx = pos[dst*3+0]-pos[src*3+0];
    const float vy = pos[dst*3+1]-pos[src*3+1];
    const float vz = pos[dst*3+2]-pos[src*3+2];
    const float d  = sqrtf(vx*vx+vy*vy+vz*vz);
    const float si = SQ3f/(d+1e-8f);
    const float s0 = vx*si, s1 = vy*si, s2 = vz*si;
    if (lane < 32) {
        inl[w][lane] = sigma[src*32+lane];
    } else {
        const float off  = (float)(lane-32)*DSP;
        const float diff = d - off;
        inl[w][lane] = expf(GCOEF*diff*diff);
    }
    __syncthreads();
    if (lane < 48) {
        float a = b1[lane];
        #pragma unroll 8
        for (int j=0;j<64;j++) a = fmaf(inl[w][j], W1[j*48+lane], a);
        hidl[w][lane] = fmaxf(a, 0.f);
    }
    __syncthreads();
    if (valid) {
        if (lane < 48) {
            float a = b2[lane];
            #pragma unroll 8
            for (int j=0;j<48;j++) a = fmaf(hidl[w][j], W2[j*48+lane], a);
            edge_emb[e*48+lane] = a;
        }
        if (lane == 0) atomicAdd(&deg[dst], 1);
        if (lane < 3)  sh1buf[e*4+lane] = (lane==0)?s0:((lane==1)?s1:s2);
    }
}

// ----------------------------------------------------------------------------
__device__ __forceinline__ void load_bfrag(const short* __restrict__ Wsw,
                                           int tile, int lane, bf16x8 (&b)[5]) {
    #pragma unroll
    for (int ks=0; ks<5; ks++)
        b[ks] = *(const bf16x8*)&Wsw[((size_t)(tile*5+ks)*64 + lane)*8];
}

__device__ __forceinline__ void mfma5(const bf16x8 (&ag)[2][5], const bf16x8 (&b)[5],
                                      f32x4& a0, f32x4& a1) {
    a0 = (f32x4){0.f,0.f,0.f,0.f};
    a1 = (f32x4){0.f,0.f,0.f,0.f};
    #pragma unroll
    for (int ks=0; ks<5; ks++) {
        a0 = __builtin_amdgcn_mfma_f32_16x16x32_bf16(ag[0][ks], b[ks], a0, 0,0,0);
        a1 = __builtin_amdgcn_mfma_f32_16x16x32_bf16(ag[1][ks], b[ks], a1, 0,0,0);
    }
}

// ----------------------------------------------------------------------------
template<int LAYER>
__global__ __launch_bounds__(256, 3)
void conv_kernel(const float* __restrict__ edge_emb, const float* __restrict__ sh1buf,
                 const int* __restrict__ ei,
                 const float* __restrict__ sin_, const float* __restrict__ vin,
                 const short* __restrict__ W1sw, const short* __restrict__ W2sw,
                 float* __restrict__ outS, float* __restrict__ outV, int E)
{
    __shared__ __align__(16) short eaB[32*192];
    __shared__ __align__(16) short hidB[32*192];
    __shared__ __align__(16) float xsT[48][36];   // [chan][edge], stride 36
    __shared__ float sh1l[32][4];
    __shared__ int   srcl[32], dstl[32];
    __shared__ __align__(16) float xvT[LAYER==2 ? 30 : 1][36];
    __shared__ __align__(16) float uT [LAYER==2 ? 10 : 1][36];
    __shared__ __align__(16) float cvT[LAYER==2 ? 30 : 1][36];

    const int t  = threadIdx.x;
    const int eb = blockIdx.x * 32;

    if (t < 32) {
        const int ge = eb + t; const int gc = (ge < E) ? ge : (E-1);
        srcl[t] = ei[gc]; dstl[t] = ei[E+gc];
    }
    if (t < 128) {
        const int e = t >> 2, k = t & 3;
        const int ge = eb + e; const int gc = (ge<E)?ge:(E-1);
        sh1l[e][k] = sh1buf[gc*4 + k];
    }
    __syncthreads();

    // ---- stage ea -> bf16 swizzled LDS (+ fp32 xsT fill for the epilogue)
    for (int p = t; p < 32*24; p += 256) {
        const int m = p / 24, s = p - m*24;
        const int k0 = s*8;
        float vals[8] = {0.f,0.f,0.f,0.f,0.f,0.f,0.f,0.f};
        if (k0 < 48) {
            const int ge = eb + m; const int gc = (ge<E)?ge:(E-1);
            const float4 a = *(const float4*)&edge_emb[gc*48 + k0];
            const float4 b = *(const float4*)&edge_emb[gc*48 + k0 + 4];
            vals[0]=a.x; vals[1]=a.y; vals[2]=a.z; vals[3]=a.w;
            vals[4]=b.x; vals[5]=b.y; vals[6]=b.z; vals[7]=b.w;
        } else if (k0 < 96) {
            const float4 a = *(const float4*)&sin_[srcl[m]*48 + (k0-48)];
            const float4 b = *(const float4*)&sin_[srcl[m]*48 + (k0-48) + 4];
            vals[0]=a.x; vals[1]=a.y; vals[2]=a.z; vals[3]=a.w;
            vals[4]=b.x; vals[5]=b.y; vals[6]=b.z; vals[7]=b.w;
            #pragma unroll
            for (int j=0;j<8;j++) xsT[k0-48+j][m] = vals[j];
        } else if (k0 < 144) {
            const float4 a = *(const float4*)&sin_[dstl[m]*48 + (k0-96)];
            const float4 b = *(const float4*)&sin_[dstl[m]*48 + (k0-96) + 4];
            vals[0]=a.x; vals[1]=a.y; vals[2]=a.z; vals[3]=a.w;
            vals[4]=b.x; vals[5]=b.y; vals[6]=b.z; vals[7]=b.w;
        } else if (k0 == 144) {
            vals[0] = 1.f;                       // bias row
        }
        union { uint4 u4; unsigned short h[8]; } pk;
        #pragma unroll
        for (int j=0;j<8;j++) pk.h[j] = f2bf(vals[j]);
        *(uint4*)&eaB[m*192 + ((s ^ (m&7))*8)] = pk.u4;
    }
    // hidB K-pad: k=144 -> 1.0 (bias row), 145..159 -> 0
    if (t < 64) {
        const int m = t >> 1, s = 18 + (t & 1);
        union { uint4 u4; unsigned short h[8]; } pk;
        pk.u4.x = pk.u4.y = pk.u4.z = pk.u4.w = 0u;
        if (s == 18) pk.h[0] = f2bf(1.f);
        *(uint4*)&hidB[m*192 + ((s ^ (m&7))*8)] = pk.u4;
    }
    if (LAYER==2) {
        for (int p=t; p<320; p+=256) {
            const int i = p >> 5, e = p & 31;
            const float x0 = vin[srcl[e]*30 + i*3+0];
            const float x1 = vin[srcl[e]*30 + i*3+1];
            const float x2 = vin[srcl[e]*30 + i*3+2];
            const float h0=sh1l[e][0], h1=sh1l[e][1], h2=sh1l[e][2];
            xvT[i*3+0][e]=x0; xvT[i*3+1][e]=x1; xvT[i*3+2][e]=x2;
            uT[i][e] = x0*h0 + x1*h1 + x2*h2;
            cvT[i*3+0][e] = x1*h2 - x2*h1;
            cvT[i*3+1][e] = x2*h0 - x0*h2;
            cvT[i*3+2][e] = x0*h1 - x1*h0;
        }
    }
    __syncthreads();

    const int wv = t >> 6, lane = t & 63;
    const int lm = lane & 15, lk = lane >> 4, lk4 = lk*4;

    // ---- GEMM1: hid = relu(ea @ W1) -> swizzled bf16 LDS
    {
        bf16x8 af[2][5];
        #pragma unroll
        for (int mt=0; mt<2; mt++) {
            const int m = mt*16 + lm;
            #pragma unroll
            for (int ks=0; ks<5; ks++)
                af[mt][ks] = *(const bf16x8*)&eaB[m*192 + (((ks*4+lk) ^ (m&7))*8)];
        }
        for (int nt = wv; nt < 9; nt += 4) {
            bf16x8 bw[5];
            load_bfrag(W1sw, nt, lane, bw);
            f32x4 a0, a1;
            mfma5(af, bw, a0, a1);
            const int c = nt*16 + lm;
            #pragma unroll
            for (int r=0; r<4; r++) {
                const int m0 = lk4 + r, m1 = 16 + lk4 + r;
                hidB[m0*192 + (((c>>3) ^ (m0&7))*8) + (c&7)] = (short)f2bf(fmaxf(a0[r], 0.f));
                hidB[m1*192 + (((c>>3) ^ (m1&7))*8) + (c&7)] = (short)f2bf(fmaxf(a1[r], 0.f));
            }
        }
    }
    __syncthreads();

    bf16x8 ag[2][5];
    #pragma unroll
    for (int mt=0; mt<2; mt++) {
        const int m = mt*16 + lm;
        #pragma unroll
        for (int ks=0; ks<5; ks++)
            ag[mt][ks] = *(const bf16x8*)&hidB[m*192 + (((ks*4+lk) ^ (m&7))*8)];
    }

    if (wv < 3) {
        // ---- this wave owns w00 output group og=wv (full i-sum in registers)
        float ms[2][4] = {{0.f,0.f,0.f,0.f},{0.f,0.f,0.f,0.f}};
        {
            bf16x8 b0[5], b1_[5];
            const int base = wv*48;
            load_bfrag(W2sw, base, lane, b0);
            for (int i=0; i<48; i+=2) {
                load_bfrag(W2sw, base+i+1, lane, b1_);
                f32x4 a0, a1;
                mfma5(ag, b0, a0, a1);
                {
                    const f32x4 x0 = *(const f32x4*)&xsT[i][lk4];
                    const f32x4 x1 = *(const f32x4*)&xsT[i][16+lk4];
                    #pragma unroll
                    for (int r=0;r<4;r++) {
                        ms[0][r] = fmaf(a0[r], x0[r], ms[0][r]);
                        ms[1][r] = fmaf(a1[r], x1[r], ms[1][r]);
                    }
                }
                if (i+2 < 48) load_bfrag(W2sw, base+i+2, lane, b0);
                mfma5(ag, b1_, a0, a1);
                {
                    const f32x4 x0 = *(const f32x4*)&xsT[i+1][lk4];
                    const f32x4 x1 = *(const f32x4*)&xsT[i+1][16+lk4];
                    #pragma unroll
                    for (int r=0;r<4;r++) {
                        ms[0][r] = fmaf(a0[r], x0[r], ms[0][r]);
                        ms[1][r] = fmaf(a1[r], x1[r], ms[1][r]);
                    }
                }
            }
        }
        if (LAYER==2) {
            // + w11s og=wv (10 tiles, uT, factor RATIO)
            bf16x8 b0[5], b1_[5];
            const int base = 144 + wv*10;
            load_bfrag(W2sw, base, lane, b0);
            for (int i=0; i<10; i+=2) {
                load_bfrag(W2sw, base+i+1, lane, b1_);
                f32x4 a0, a1;
                mfma5(ag, b0, a0, a1);
                {
                    const f32x4 u0 = *(const f32x4*)&uT[i][lk4];
                    const f32x4 u1 = *(const f32x4*)&uT[i][16+lk4];
                    #pragma unroll
                    for (int r=0;r<4;r++) {
                        ms[0][r] = fmaf(a0[r]*RATIO, u0[r], ms[0][r]);
                        ms[1][r] = fmaf(a1[r]*RATIO, u1[r], ms[1][r]);
                    }
                }
                if (i+2 < 10) load_bfrag(W2sw, base+i+2, lane, b0);
                mfma5(ag, b1_, a0, a1);
                {
                    const f32x4 u0 = *(const f32x4*)&uT[i+1][lk4];
                    const f32x4 u1 = *(const f32x4*)&uT[i+1][16+lk4];
                    #pragma unroll
                    for (int r=0;r<4;r++) {
                        ms[0][r] = fmaf(a0[r]*RATIO, u0[r], ms[0][r]);
                        ms[1][r] = fmaf(a1[r]*RATIO, u1[r], ms[1][r]);
                    }
                }
            }
        }
        // scatter
        const float scale = (LAYER==1) ? INV1 : NAc;
        const int   strd  = (LAYER==1) ? 48 : 108;
        const int o = wv*16 + lm;
        #pragma unroll
        for (int r=0;r<4;r++) {
            const int e0 = lk4+r, e1 = 16+lk4+r;
            if (eb+e0 < E) unsafeAtomicAdd(&outS[(size_t)dstl[e0]*strd + o], ms[0][r]*scale);
            if (eb+e1 < E) unsafeAtomicAdd(&outS[(size_t)dstl[e1]*strd + o], ms[1][r]*scale);
        }
    } else {
        // ---- wave 3 owns the vector-channel outputs
        float vc[2][4] = {{0.f,0.f,0.f,0.f},{0.f,0.f,0.f,0.f}};
        {
            bf16x8 b0[5], b1_[5];
            const int base = (LAYER==1) ? 144 : 174;   // w01
            load_bfrag(W2sw, base, lane, b0);
            for (int i=0; i<48; i+=2) {
                load_bfrag(W2sw, base+i+1, lane, b1_);
                f32x4 a0, a1;
                mfma5(ag, b0, a0, a1);
                {
                    const f32x4 x0 = *(const f32x4*)&xsT[i][lk4];
                    const f32x4 x1 = *(const f32x4*)&xsT[i][16+lk4];
                    #pragma unroll
                    for (int r=0;r<4;r++) {
                        vc[0][r] = fmaf(a0[r], x0[r], vc[0][r]);
                        vc[1][r] = fmaf(a1[r], x1[r], vc[1][r]);
                    }
                }
                if (i+2 < 48) load_bfrag(W2sw, base+i+2, lane, b0);
                mfma5(ag, b1_, a0, a1);
                {
                    const f32x4 x0 = *(const f32x4*)&xsT[i+1][lk4];
                    const f32x4 x1 = *(const f32x4*)&xsT[i+1][16+lk4];
                    #pragma unroll
                    for (int r=0;r<4;r++) {
                        vc[0][r] = fmaf(a0[r], x0[r], vc[0][r]);
                        vc[1][r] = fmaf(a1[r], x1[r], vc[1][r]);
                    }
                }
            }
        }
        if (LAYER==1) {
            if (lm < 10) {
                #pragma unroll
                for (int r=0;r<4;r++) {
                    const int e0 = lk4+r, e1 = 16+lk4+r;
                    const float v0 = vc[0][r]*INV1, v1 = vc[1][r]*INV1;
                    #pragma unroll
                    for (int d=0; d<3; d++) {
                        if (eb+e0 < E) unsafeAtomicAdd(&outV[(size_t)dstl[e0]*30 + lm*3 + d], v0*sh1l[e0][d]);
                        if (eb+e1 < E) unsafeAtomicAdd(&outV[(size_t)dstl[e1]*30 + lm*3 + d], v1*sh1l[e1][d]);
                    }
                }
            }
        } else {
            float m3[2][4][3] = {};
            {   // w10: tiles 222..232, xvT
                bf16x8 b0[5], b1_[5];
                load_bfrag(W2sw, 222, lane, b0);
                for (int i=0; i<10; i+=2) {
                    load_bfrag(W2sw, 222+i+1, lane, b1_);
                    f32x4 a0, a1;
                    mfma5(ag, b0, a0, a1);
                    #pragma unroll
                    for (int d=0; d<3; d++) {
                        const f32x4 x0 = *(const f32x4*)&xvT[i*3+d][lk4];
                        const f32x4 x1 = *(const f32x4*)&xvT[i*3+d][16+lk4];
                        #pragma unroll
                        for (int r=0;r<4;r++) {
                            m3[0][r][d] = fmaf(a0[r], x0[r], m3[0][r][d]);
                            m3[1][r][d] = fmaf(a1[r], x1[r], m3[1][r][d]);
                        }
                    }
                    if (i+2 < 10) load_bfrag(W2sw, 222+i+2, lane, b0);
                    mfma5(ag, b1_, a0, a1);
                    #pragma unroll
                    for (int d=0; d<3; d++) {
                        const f32x4 x0 = *(const f32x4*)&xvT[(i+1)*3+d][lk4];
                        const f32x4 x1 = *(const f32x4*)&xvT[(i+1)*3+d][16+lk4];
                        #pragma unroll
                        for (int r=0;r<4;r++) {
                            m3[0][r][d] = fmaf(a0[r], x0[r], m3[0][r][d]);
                            m3[1][r][d] = fmaf(a1[r], x1[r], m3[1][r][d]);
                        }
                    }
                }
            }
            if (lm < 10) {
                #pragma unroll
                for (int r=0;r<4;r++) {
                    const int e0 = lk4+r, e1 = 16+lk4+r;
                    const float v0 = vc[0][r]*NAc, v1 = vc[1][r]*NAc;
                    #pragma unroll
                    for (int d=0; d<3; d++) {
                        if (eb+e0 < E)
                            unsafeAtomicAdd(&outS[(size_t)dstl[e0]*108 + 48 + lm*3 + d],
                                            v0*sh1l[e0][d] + m3[0][r][d]*NBc);
                        if (eb+e1 < E)
                            unsafeAtomicAdd(&outS[(size_t)dstl[e1]*108 + 48 + lm*3 + d],
                                            v1*sh1l[e1][d] + m3[1][r][d]*NBc);
                    }
                }
            }
            // w11p: tiles 232..242, cvT (reuse m3)
            #pragma unroll
            for (int a=0;a<2;a++)
                #pragma unroll
                for (int r=0;r<4;r++)
                    #pragma unroll
                    for (int d=0;d<3;d++) m3[a][r][d] = 0.f;
            {
                bf16x8 b0[5], b1_[5];
                load_bfrag(W2sw, 232, lane, b0);
                for (int i=0; i<10; i+=2) {
                    load_bfrag(W2sw, 232+i+1, lane, b1_);
                    f32x4 a0, a1;
                    mfma5(ag, b0, a0, a1);
                    #pragma unroll
                    for (int d=0; d<3; d++) {
                        const f32x4 x0 = *(const f32x4*)&cvT[i*3+d][lk4];
                        const f32x4 x1 = *(const f32x4*)&cvT[i*3+d][16+lk4];
                        #pragma unroll
                        for (int r=0;r<4;r++) {
                            m3[0][r][d] = fmaf(a0[r], x0[r], m3[0][r][d]);
                            m3[1][r][d] = fmaf(a1[r], x1[r], m3[1][r][d]);
                        }
                    }
                    if (i+2 < 10) load_bfrag(W2sw, 232+i+2, lane, b0);
                    mfma5(ag, b1_, a0, a1);
                    #pragma unroll
                    for (int d=0; d<3; d++) {
                        const f32x4 x0 = *(const f32x4*)&cvT[(i+1)*3+d][lk4];
                        const f32x4 x1 = *(const f32x4*)&cvT[(i+1)*3+d][16+lk4];
                        #pragma unroll
                        for (int r=0;r<4;r++) {
                            m3[0][r][d] = fmaf(a0[r], x0[r], m3[0][r][d]);
                            m3[1][r][d] = fmaf(a1[r], x1[r], m3[1][r][d]);
                        }
                    }
                }
            }
            if (lm < 10) {
                #pragma unroll
                for (int r=0;r<4;r++) {
                    const int e0 = lk4+r, e1 = 16+lk4+r;
                    #pragma unroll
                    for (int d=0; d<3; d++) {
                        if (eb+e0 < E)
                            unsafeAtomicAdd(&outS[(size_t)dstl[e0]*108 + 78 + lm*3 + d], m3[0][r][d]*C20);
                        if (eb+e1 < E)
                            unsafeAtomicAdd(&outS[(size_t)dstl[e1]*108 + 78 + lm*3 + d], m3[1][r][d]*C20);
                    }
                }
            }
        }
    }
}

// ----------------------------------------------------------------------------
__global__ __launch_bounds__(256)
void fin1_kernel(const float* __restrict__ node_s, const int* __restrict__ deg,
                 float* __restrict__ s1, float* __restrict__ v1, int Nn)
{
    const int p = blockIdx.x*256 + threadIdx.x;
    const int totS = Nn*48;
    if (p < totS) {
        const int n = p/48;
        const int dgi = deg[n];
        const float dg = (float)(dgi > 1 ? dgi : 1);
        s1[p] = node_s[p] + s1[p]/dg;
    } else {
        const int q = p - totS;
        if (q < Nn*30) {
            const int n = q/30;
            const int dgi = deg[n];
            const float dg = (float)(dgi > 1 ? dgi : 1);
            v1[q] = v1[q]/dg;
        }
    }
}

__global__ __launch_bounds__(256)
void fin2_kernel(const float* __restrict__ s1, const float* __restrict__ v1,
                 const int* __restrict__ deg, float* __restrict__ out, int Nn)
{
    const int p = blockIdx.x*256 + threadIdx.x;
    if (p >= Nn*108) return;
    const int n = p/108, c = p - n*108;
    const int dgi = deg[n];
    const float dg = (float)(dgi > 1 ? dgi : 1);
    const float acc = out[p]/dg;
    if (c < 48)      out[p] = s1[n*48+c] + acc;
    else if (c < 78) out[p] = v1[n*30 + (c-48)] + acc;
    else             out[p] = acc;
}

// ----------------------------------------------------------------------------
extern "C" void kernel_launch(void* const* d_in, const int* in_sizes, int n_in,
                              void* d_out, int out_size, void* d_ws, size_t ws_size,
                              hipStream_t stream)
{
    const float* pos    = (const float*)d_in[0];
    const float* sigma  = (const float*)d_in[1];
    const float* node_s = (const float*)d_in[2];
    const float* eW1  = (const float*)d_in[3];
    const float* eb1  = (const float*)d_in[4];
    const float* eW2  = (const float*)d_in[5];
    const float* eb2  = (const float*)d_in[6];
    const float* f1W1 = (const float*)d_in[7];
    const float* f1b1 = (const float*)d_in[8];
    const float* f1W2 = (const float*)d_in[9];
    const float* f1b2 = (const float*)d_in[10];
    const float* f2W1 = (const float*)d_in[11];
    const float* f2b1 = (const float*)d_in[12];
    const float* f2W2 = (const float*)d_in[13];
    const float* f2b2 = (const float*)d_in[14];
    const int*   ei   = (const int*)d_in[15];
    const int Nn = in_sizes[0]/3;
    const int E  = in_sizes[15]/2;
    float* out = (float*)d_out;

    char* ws = (char*)d_ws;
    float* edge_emb = (float*)ws;  ws += (size_t)E*48*sizeof(float);
    float* sh1buf   = (float*)ws;  ws += (size_t)E*4*sizeof(float);
    float* s1       = (float*)ws;  ws += (size_t)Nn*48*sizeof(float);
    float* v1       = (float*)ws;  ws += (size_t)Nn*30*sizeof(float);
    int*   deg      = (int*)ws;    ws += (size_t)Nn*sizeof(int);
    short* W1sw     = (short*)ws;  ws += (size_t)9*5*64*8*sizeof(short);
    short* W2sw     = (short*)ws;  ws += (size_t)242*5*64*8*sizeof(short);

    hipMemsetAsync(s1,  0, (size_t)Nn*48*sizeof(float), stream);
    hipMemsetAsync(v1,  0, (size_t)Nn*30*sizeof(float), stream);
    hipMemsetAsync(deg, 0, (size_t)Nn*sizeof(int),      stream);
    hipMemsetAsync(out, 0, (size_t)Nn*108*sizeof(float), stream);

    edge_kernel<<<(E+3)/4, 256, 0, stream>>>(pos, sigma, ei, eW1, eb1, eW2, eb2,
                                             edge_emb, sh1buf, deg, E);

    cvt_swz<<<(9*5*64+255)/256,   256, 0, stream>>>(f1W1, f1b1, W1sw, 144, 9, 0);
    cvt_swz<<<(192*5*64+255)/256, 256, 0, stream>>>(f1W2, f1b2, W2sw, 2784, 192, 1);

    conv_kernel<1><<<(E+31)/32, 256, 0, stream>>>(edge_emb, sh1buf, ei, node_s, nullptr,
                                                  W1sw, W2sw, s1, v1, E);
    fin1_kernel<<<((size_t)Nn*78 + 255)/256, 256, 0, stream>>>(node_s, deg, s1, v1, Nn);

    cvt_swz<<<(9*5*64+255)/256,   256, 0, stream>>>(f2W1, f2b1, W1sw, 144, 9, 0);
    cvt_swz<<<(242*5*64+255)/256, 256, 0, stream>>>(f2W2, f2b2, W2sw, 3464, 242, 2);

    conv_kernel<2><<<(E+31)/32, 256, 0, stream>>>(edge_emb, sh1buf, ei, s1, v1,
                                                  W1sw, W2sw, out, nullptr, E);
    fin2_kernel<<<((size_t)Nn*108 + 255)/256, 256, 0, stream>>>(s1, v1, deg, out, Nn);
}

// Round 6
// 484.123 us; speedup vs baseline: 2.8120x; 2.7413x over previous
//
#include <hip/hip_runtime.h>
#include <math.h>

// AAModel round 6: round-3's register-friendly region() loop (compiler-owned
// prefetch scheduling, no waves-per-EU pin) + round-4's wave-owns-output-group
// decomposition (register-complete TP sums, no LDS partial pool, no cross-wave
// reduce, native f32 atomic scatter).
// Round 4/5 lesson: min-waves attr + manual 2-deep prefetch => scratch spills
// (FETCH/WRITE ~700-1000MB). Round 3's region() ran the same dataflow at 88
// VGPR, zero scratch. Recombine the good halves.

constexpr float SQ3f = 1.7320508075688772f;
constexpr float INV1 = 0.14433756729740643f;  // 1/sqrt(48)
constexpr float NAc  = 0.10206207261596575f;  // 1/sqrt(2*48)
constexpr float NBc  = 0.22360679774997896f;  // 1/sqrt(2*10)
constexpr float C20  = 0.22360679774997896f;  // 1/sqrt(20)
constexpr float RATIO= 1.2649110640673518f;   // (NBc/sqrt3)/NAc
constexpr float DSP  = 30.0f/31.0f;
constexpr float GCOEF= -0.5f/(DSP*DSP);

typedef __attribute__((ext_vector_type(8))) short bf16x8;
typedef __attribute__((ext_vector_type(4))) float f32x4;

__device__ __forceinline__ unsigned short f2bf(float x) {
    unsigned u = __builtin_bit_cast(unsigned, x);
    u += 0x7fffu + ((u >> 16) & 1u);     // RNE
    return (unsigned short)(u >> 16);
}

// tile/lane-slot -> original W2 column (or -1 = padding lane)
__device__ __forceinline__ int colmap(int layer, int t, int lm) {
    if (layer == 0) return t*16 + lm;                           // W1 identity
    if (layer == 1) {
        if (t < 144) { const int og=t/48, i=t-og*48; return i*48 + og*16 + lm; }      // w00
        const int i = t-144; return (lm<10) ? 2304 + i*10 + lm : -1;                  // w01
    }
    if (t < 144) { const int og=t/48, i=t-og*48; return i*48 + og*16 + lm; }          // w00
    if (t < 174) { const int s=t-144, og=s/10, i=s-og*10; return 2884 + i*48 + og*16 + lm; } // w11s
    if (t < 222) { const int i=t-174; return (lm<10) ? 2304 + i*10 + lm : -1; }       // w01
    if (t < 232) { const int i=t-222; return (lm<10) ? 2784 + i*10 + lm : -1; }       // w10
    { const int i=t-232; return (lm<10) ? 3364 + i*10 + lm : -1; }                    // w11p
}

__global__ __launch_bounds__(256)
void cvt_swz(const float* __restrict__ W, const float* __restrict__ bias,
             short* __restrict__ Wsw, int ncol, int ntile, int layer)
{
    const int gid = blockIdx.x*256 + threadIdx.x;
    const int g = gid >> 6, lane = gid & 63;
    if (g >= ntile*5) return;
    const int tile = g/5, ks = g - tile*5;
    const int c  = colmap(layer, tile, lane & 15);
    const int k0 = ks*32 + (lane >> 4)*8;
    union { uint4 u4; unsigned short h[8]; } pk;
    #pragma unroll
    for (int j=0;j<8;j++) {
        const int k = k0 + j;
        float v = 0.f;
        if (c >= 0) {
            if (k < 144)       v = W[(size_t)k*ncol + c];
            else if (k == 144) v = bias[c];
        }
        pk.h[j] = f2bf(v);
    }
    *(uint4*)&Wsw[((size_t)g*64 + lane)*8] = pk.u4;
}

// ----------------------------------------------------------------------------
__global__ __launch_bounds__(256)
void edge_kernel(const float* __restrict__ pos, const float* __restrict__ sigma,
                 const int* __restrict__ ei,
                 const float* __restrict__ W1, const float* __restrict__ b1,
                 const float* __restrict__ W2, const float* __restrict__ b2,
                 float* __restrict__ edge_emb, float* __restrict__ sh1buf,
                 int* __restrict__ deg, int E)
{
    __shared__ float inl[4][64];
    __shared__ float hidl[4][48];
    const int w    = threadIdx.x >> 6;
    const int lane = threadIdx.x & 63;
    const int e    = blockIdx.x*4 + w;
    const bool valid = (e < E);
    const int ec = valid ? e : 0;
    const int src = ei[ec], dst = ei[E+ec];
    const float vx = pos[dst*3+0]-pos[src*3+0];
    const float vy = pos[dst*3+1]-pos[src*3+1];
    const float vz = pos[dst*3+2]-pos[src*3+2];
    const float d  = sqrtf(vx*vx+vy*vy+vz*vz);
    const float si = SQ3f/(d+1e-8f);
    const float s0 = vx*si, s1 = vy*si, s2 = vz*si;
    if (lane < 32) {
        inl[w][lane] = sigma[src*32+lane];
    } else {
        const float off  = (float)(lane-32)*DSP;
        const float diff = d - off;
        inl[w][lane] = expf(GCOEF*diff*diff);
    }
    __syncthreads();
    if (lane < 48) {
        float a = b1[lane];
        #pragma unroll 8
        for (int j=0;j<64;j++) a = fmaf(inl[w][j], W1[j*48+lane], a);
        hidl[w][lane] = fmaxf(a, 0.f);
    }
    __syncthreads();
    if (valid) {
        if (lane < 48) {
            float a = b2[lane];
            #pragma unroll 8
            for (int j=0;j<48;j++) a = fmaf(hidl[w][j], W2[j*48+lane], a);
            edge_emb[e*48+lane] = a;
        }
        if (lane == 0) atomicAdd(&deg[dst], 1);
        if (lane < 3)  sh1buf[e*4+lane] = (lane==0)?s0:((lane==1)?s1:s2);
    }
}

// ----------------------------------------------------------------------------
__device__ __forceinline__ void load_bfrag(const short* __restrict__ Wsw,
                                           int tile, int lane, bf16x8 (&b)[5]) {
    #pragma unroll
    for (int ks=0; ks<5; ks++)
        b[ks] = *(const bf16x8*)&Wsw[((size_t)(tile*5+ks)*64 + lane)*8];
}

__device__ __forceinline__ void mfma5(const bf16x8 (&ag)[2][5], const bf16x8 (&b)[5],
                                      f32x4& a0, f32x4& a1) {
    a0 = (f32x4){0.f,0.f,0.f,0.f};
    a1 = (f32x4){0.f,0.f,0.f,0.f};
    #pragma unroll
    for (int ks=0; ks<5; ks++) {
        a0 = __builtin_amdgcn_mfma_f32_16x16x32_bf16(ag[0][ks], b[ks], a0, 0,0,0);
        a1 = __builtin_amdgcn_mfma_f32_16x16x32_bf16(ag[1][ks], b[ks], a1, 0,0,0);
    }
}

// one wave-owned region: tiles base..base+count, single-step prefetch
// (compiler-scheduled, round-3-proven register pressure)
template<typename F>
__device__ __forceinline__ void region1(const short* __restrict__ Wsw, int base,
                                        int count, int lane,
                                        const bf16x8 (&ag)[2][5], F&& upd)
{
    bf16x8 bc[5], bn[5];
    load_bfrag(Wsw, base, lane, bc);
    for (int i=0; i<count; ++i) {
        if (i+1 < count) load_bfrag(Wsw, base+i+1, lane, bn);
        f32x4 a0, a1;
        mfma5(ag, bc, a0, a1);
        upd(i, a0, a1);
        #pragma unroll
        for (int ks=0; ks<5; ks++) bc[ks] = bn[ks];
    }
}

// ----------------------------------------------------------------------------
template<int LAYER>
__global__ __launch_bounds__(256)
void conv_kernel(const float* __restrict__ edge_emb, const float* __restrict__ sh1buf,
                 const int* __restrict__ ei,
                 const float* __restrict__ sin_, const float* __restrict__ vin,
                 const short* __restrict__ W1sw, const short* __restrict__ W2sw,
                 float* __restrict__ outS, float* __restrict__ outV, int E)
{
    __shared__ __align__(16) short eaB[32*192];
    __shared__ __align__(16) short hidB[32*192];
    __shared__ __align__(16) float xsT[48][36];   // [chan][edge], stride 36 (16B-aligned rows)
    __shared__ float sh1l[32][4];
    __shared__ int   srcl[32], dstl[32];
    __shared__ __align__(16) float xvT[LAYER==2 ? 30 : 1][36];
    __shared__ __align__(16) float uT [LAYER==2 ? 10 : 1][36];
    __shared__ __align__(16) float cvT[LAYER==2 ? 30 : 1][36];

    const int t  = threadIdx.x;
    const int eb = blockIdx.x * 32;

    if (t < 32) {
        const int ge = eb + t; const int gc = (ge < E) ? ge : (E-1);
        srcl[t] = ei[gc]; dstl[t] = ei[E+gc];
    }
    if (t < 128) {
        const int e = t >> 2, k = t & 3;
        const int ge = eb + e; const int gc = (ge<E)?ge:(E-1);
        sh1l[e][k] = sh1buf[gc*4 + k];
    }
    __syncthreads();

    // ---- stage ea -> bf16 swizzled LDS (+ fp32 xsT fill for the epilogue)
    for (int p = t; p < 32*24; p += 256) {
        const int m = p / 24, s = p - m*24;
        const int k0 = s*8;
        float vals[8] = {0.f,0.f,0.f,0.f,0.f,0.f,0.f,0.f};
        if (k0 < 48) {
            const int ge = eb + m; const int gc = (ge<E)?ge:(E-1);
            const float4 a = *(const float4*)&edge_emb[gc*48 + k0];
            const float4 b = *(const float4*)&edge_emb[gc*48 + k0 + 4];
            vals[0]=a.x; vals[1]=a.y; vals[2]=a.z; vals[3]=a.w;
            vals[4]=b.x; vals[5]=b.y; vals[6]=b.z; vals[7]=b.w;
        } else if (k0 < 96) {
            const float4 a = *(const float4*)&sin_[srcl[m]*48 + (k0-48)];
            const float4 b = *(const float4*)&sin_[srcl[m]*48 + (k0-48) + 4];
            vals[0]=a.x; vals[1]=a.y; vals[2]=a.z; vals[3]=a.w;
            vals[4]=b.x; vals[5]=b.y; vals[6]=b.z; vals[7]=b.w;
            #pragma unroll
            for (int j=0;j<8;j++) xsT[k0-48+j][m] = vals[j];
        } else if (k0 < 144) {
            const float4 a = *(const float4*)&sin_[dstl[m]*48 + (k0-96)];
            const float4 b = *(const float4*)&sin_[dstl[m]*48 + (k0-96) + 4];
            vals[0]=a.x; vals[1]=a.y; vals[2]=a.z; vals[3]=a.w;
            vals[4]=b.x; vals[5]=b.y; vals[6]=b.z; vals[7]=b.w;
        } else if (k0 == 144) {
            vals[0] = 1.f;                       // bias row
        }
        union { uint4 u4; unsigned short h[8]; } pk;
        #pragma unroll
        for (int j=0;j<8;j++) pk.h[j] = f2bf(vals[j]);
        *(uint4*)&eaB[m*192 + ((s ^ (m&7))*8)] = pk.u4;
    }
    // hidB K-pad: k=144 -> 1.0 (bias row), 145..159 -> 0
    if (t < 64) {
        const int m = t >> 1, s = 18 + (t & 1);
        union { uint4 u4; unsigned short h[8]; } pk;
        pk.u4.x = pk.u4.y = pk.u4.z = pk.u4.w = 0u;
        if (s == 18) pk.h[0] = f2bf(1.f);
        *(uint4*)&hidB[m*192 + ((s ^ (m&7))*8)] = pk.u4;
    }
    if (LAYER==2) {
        for (int p=t; p<320; p+=256) {
            const int i = p >> 5, e = p & 31;
            const float x0 = vin[srcl[e]*30 + i*3+0];
            const float x1 = vin[srcl[e]*30 + i*3+1];
            const float x2 = vin[srcl[e]*30 + i*3+2];
            const float h0=sh1l[e][0], h1=sh1l[e][1], h2=sh1l[e][2];
            xvT[i*3+0][e]=x0; xvT[i*3+1][e]=x1; xvT[i*3+2][e]=x2;
            uT[i][e] = x0*h0 + x1*h1 + x2*h2;
            cvT[i*3+0][e] = x1*h2 - x2*h1;
            cvT[i*3+1][e] = x2*h0 - x0*h2;
            cvT[i*3+2][e] = x0*h1 - x1*h0;
        }
    }
    __syncthreads();

    const int wv = t >> 6, lane = t & 63;
    const int lm = lane & 15, lk = lane >> 4, lk4 = lk*4;

    // ---- GEMM1: hid = relu(ea @ W1) -> swizzled bf16 LDS
    {
        bf16x8 af[2][5];
        #pragma unroll
        for (int mt=0; mt<2; mt++) {
            const int m = mt*16 + lm;
            #pragma unroll
            for (int ks=0; ks<5; ks++)
                af[mt][ks] = *(const bf16x8*)&eaB[m*192 + (((ks*4+lk) ^ (m&7))*8)];
        }
        for (int nt = wv; nt < 9; nt += 4) {
            bf16x8 bw[5];
            load_bfrag(W1sw, nt, lane, bw);
            f32x4 a0, a1;
            mfma5(af, bw, a0, a1);
            const int c = nt*16 + lm;
            #pragma unroll
            for (int r=0; r<4; r++) {
                const int m0 = lk4 + r, m1 = 16 + lk4 + r;
                hidB[m0*192 + (((c>>3) ^ (m0&7))*8) + (c&7)] = (short)f2bf(fmaxf(a0[r], 0.f));
                hidB[m1*192 + (((c>>3) ^ (m1&7))*8) + (c&7)] = (short)f2bf(fmaxf(a1[r], 0.f));
            }
        }
    }
    __syncthreads();

    bf16x8 ag[2][5];
    #pragma unroll
    for (int mt=0; mt<2; mt++) {
        const int m = mt*16 + lm;
        #pragma unroll
        for (int ks=0; ks<5; ks++)
            ag[mt][ks] = *(const bf16x8*)&hidB[m*192 + (((ks*4+lk) ^ (m&7))*8)];
    }

    if (wv < 3) {
        // ---- wave owns w00 output group og=wv (full i-sum in registers)
        float ms[2][4] = {{0.f,0.f,0.f,0.f},{0.f,0.f,0.f,0.f}};
        region1(W2sw, wv*48, 48, lane, ag, [&](int i, f32x4 a0, f32x4 a1) {
            const f32x4 x0 = *(const f32x4*)&xsT[i][lk4];
            const f32x4 x1 = *(const f32x4*)&xsT[i][16+lk4];
            #pragma unroll
            for (int r=0;r<4;r++) {
                ms[0][r] = fmaf(a0[r], x0[r], ms[0][r]);
                ms[1][r] = fmaf(a1[r], x1[r], ms[1][r]);
            }
        });
        if (LAYER==2) {
            region1(W2sw, 144 + wv*10, 10, lane, ag, [&](int i, f32x4 a0, f32x4 a1) {
                const f32x4 u0 = *(const f32x4*)&uT[i][lk4];
                const f32x4 u1 = *(const f32x4*)&uT[i][16+lk4];
                #pragma unroll
                for (int r=0;r<4;r++) {
                    ms[0][r] = fmaf(a0[r]*RATIO, u0[r], ms[0][r]);
                    ms[1][r] = fmaf(a1[r]*RATIO, u1[r], ms[1][r]);
                }
            });
        }
        const float scale = (LAYER==1) ? INV1 : NAc;
        const int   strd  = (LAYER==1) ? 48 : 108;
        const int o = wv*16 + lm;
        #pragma unroll
        for (int r=0;r<4;r++) {
            const int e0 = lk4+r, e1 = 16+lk4+r;
            if (eb+e0 < E) unsafeAtomicAdd(&outS[(size_t)dstl[e0]*strd + o], ms[0][r]*scale);
            if (eb+e1 < E) unsafeAtomicAdd(&outS[(size_t)dstl[e1]*strd + o], ms[1][r]*scale);
        }
    } else {
        // ---- wave 3 owns the vector-channel outputs
        float vc[2][4] = {{0.f,0.f,0.f,0.f},{0.f,0.f,0.f,0.f}};
        region1(W2sw, (LAYER==1) ? 144 : 174, 48, lane, ag, [&](int i, f32x4 a0, f32x4 a1) {
            const f32x4 x0 = *(const f32x4*)&xsT[i][lk4];
            const f32x4 x1 = *(const f32x4*)&xsT[i][16+lk4];
            #pragma unroll
            for (int r=0;r<4;r++) {
                vc[0][r] = fmaf(a0[r], x0[r], vc[0][r]);
                vc[1][r] = fmaf(a1[r], x1[r], vc[1][r]);
            }
        });
        if (LAYER==1) {
            if (lm < 10) {
                #pragma unroll
                for (int r=0;r<4;r++) {
                    const int e0 = lk4+r, e1 = 16+lk4+r;
                    const float v0 = vc[0][r]*INV1, v1 = vc[1][r]*INV1;
                    #pragma unroll
                    for (int d=0; d<3; d++) {
                        if (eb+e0 < E) unsafeAtomicAdd(&outV[(size_t)dstl[e0]*30 + lm*3 + d], v0*sh1l[e0][d]);
                        if (eb+e1 < E) unsafeAtomicAdd(&outV[(size_t)dstl[e1]*30 + lm*3 + d], v1*sh1l[e1][d]);
                    }
                }
            }
        } else {
            {   // w10 (xvT), combined scatter with vc
                float m3[2][4][3] = {};
                region1(W2sw, 222, 10, lane, ag, [&](int i, f32x4 a0, f32x4 a1) {
                    #pragma unroll
                    for (int d=0; d<3; d++) {
                        const f32x4 x0 = *(const f32x4*)&xvT[i*3+d][lk4];
                        const f32x4 x1 = *(const f32x4*)&xvT[i*3+d][16+lk4];
                        #pragma unroll
                        for (int r=0;r<4;r++) {
                            m3[0][r][d] = fmaf(a0[r], x0[r], m3[0][r][d]);
                            m3[1][r][d] = fmaf(a1[r], x1[r], m3[1][r][d]);
                        }
                    }
                });
                if (lm < 10) {
                    #pragma unroll
                    for (int r=0;r<4;r++) {
                        const int e0 = lk4+r, e1 = 16+lk4+r;
                        const float v0 = vc[0][r]*NAc, v1 = vc[1][r]*NAc;
                        #pragma unroll
                        for (int d=0; d<3; d++) {
                            if (eb+e0 < E)
                                unsafeAtomicAdd(&outS[(size_t)dstl[e0]*108 + 48 + lm*3 + d],
                                                v0*sh1l[e0][d] + m3[0][r][d]*NBc);
                            if (eb+e1 < E)
                                unsafeAtomicAdd(&outS[(size_t)dstl[e1]*108 + 48 + lm*3 + d],
                                                v1*sh1l[e1][d] + m3[1][r][d]*NBc);
                        }
                    }
                }
            }
            {   // w11p (cvT)
                float m3[2][4][3] = {};
                region1(W2sw, 232, 10, lane, ag, [&](int i, f32x4 a0, f32x4 a1) {
                    #pragma unroll
                    for (int d=0; d<3; d++) {
                        const f32x4 x0 = *(const f32x4*)&cvT[i*3+d][lk4];
                        const f32x4 x1 = *(const f32x4*)&cvT[i*3+d][16+lk4];
                        #pragma unroll
                        for (int r=0;r<4;r++) {
                            m3[0][r][d] = fmaf(a0[r], x0[r], m3[0][r][d]);
                            m3[1][r][d] = fmaf(a1[r], x1[r], m3[1][r][d]);
                        }
                    }
                });
                if (lm < 10) {
                    #pragma unroll
                    for (int r=0;r<4;r++) {
                        const int e0 = lk4+r, e1 = 16+lk4+r;
                        #pragma unroll
                        for (int d=0; d<3; d++) {
                            if (eb+e0 < E)
                                unsafeAtomicAdd(&outS[(size_t)dstl[e0]*108 + 78 + lm*3 + d], m3[0][r][d]*C20);
                            if (eb+e1 < E)
                                unsafeAtomicAdd(&outS[(size_t)dstl[e1]*108 + 78 + lm*3 + d], m3[1][r][d]*C20);
                        }
                    }
                }
            }
        }
    }
}

// ----------------------------------------------------------------------------
__global__ __launch_bounds__(256)
void fin1_kernel(const float* __restrict__ node_s, const int* __restrict__ deg,
                 float* __restrict__ s1, float* __restrict__ v1, int Nn)
{
    const int p = blockIdx.x*256 + threadIdx.x;
    const int totS = Nn*48;
    if (p < totS) {
        const int n = p/48;
        const int dgi = deg[n];
        const float dg = (float)(dgi > 1 ? dgi : 1);
        s1[p] = node_s[p] + s1[p]/dg;
    } else {
        const int q = p - totS;
        if (q < Nn*30) {
            const int n = q/30;
            const int dgi = deg[n];
            const float dg = (float)(dgi > 1 ? dgi : 1);
            v1[q] = v1[q]/dg;
        }
    }
}

__global__ __launch_bounds__(256)
void fin2_kernel(const float* __restrict__ s1, const float* __restrict__ v1,
                 const int* __restrict__ deg, float* __restrict__ out, int Nn)
{
    const int p = blockIdx.x*256 + threadIdx.x;
    if (p >= Nn*108) return;
    const int n = p/108, c = p - n*108;
    const int dgi = deg[n];
    const float dg = (float)(dgi > 1 ? dgi : 1);
    const float acc = out[p]/dg;
    if (c < 48)      out[p] = s1[n*48+c] + acc;
    else if (c < 78) out[p] = v1[n*30 + (c-48)] + acc;
    else             out[p] = acc;
}

// ----------------------------------------------------------------------------
extern "C" void kernel_launch(void* const* d_in, const int* in_sizes, int n_in,
                              void* d_out, int out_size, void* d_ws, size_t ws_size,
                              hipStream_t stream)
{
    const float* pos    = (const float*)d_in[0];
    const float* sigma  = (const float*)d_in[1];
    const float* node_s = (const float*)d_in[2];
    const float* eW1  = (const float*)d_in[3];
    const float* eb1  = (const float*)d_in[4];
    const float* eW2  = (const float*)d_in[5];
    const float* eb2  = (const float*)d_in[6];
    const float* f1W1 = (const float*)d_in[7];
    const float* f1b1 = (const float*)d_in[8];
    const float* f1W2 = (const float*)d_in[9];
    const float* f1b2 = (const float*)d_in[10];
    const float* f2W1 = (const float*)d_in[11];
    const float* f2b1 = (const float*)d_in[12];
    const float* f2W2 = (const float*)d_in[13];
    const float* f2b2 = (const float*)d_in[14];
    const int*   ei   = (const int*)d_in[15];
    const int Nn = in_sizes[0]/3;
    const int E  = in_sizes[15]/2;
    float* out = (float*)d_out;

    char* ws = (char*)d_ws;
    float* edge_emb = (float*)ws;  ws += (size_t)E*48*sizeof(float);
    float* sh1buf   = (float*)ws;  ws += (size_t)E*4*sizeof(float);
    float* s1       = (float*)ws;  ws += (size_t)Nn*48*sizeof(float);
    float* v1       = (float*)ws;  ws += (size_t)Nn*30*sizeof(float);
    int*   deg      = (int*)ws;    ws += (size_t)Nn*sizeof(int);
    short* W1sw     = (short*)ws;  ws += (size_t)9*5*64*8*sizeof(short);
    short* W2sw     = (short*)ws;  ws += (size_t)242*5*64*8*sizeof(short);

    hipMemsetAsync(s1,  0, (size_t)Nn*48*sizeof(float), stream);
    hipMemsetAsync(v1,  0, (size_t)Nn*30*sizeof(float), stream);
    hipMemsetAsync(deg, 0, (size_t)Nn*sizeof(int),      stream);
    hipMemsetAsync(out, 0, (size_t)Nn*108*sizeof(float), stream);

    edge_kernel<<<(E+3)/4, 256, 0, stream>>>(pos, sigma, ei, eW1, eb1, eW2, eb2,
                                             edge_emb, sh1buf, deg, E);

    cvt_swz<<<(9*5*64+255)/256,   256, 0, stream>>>(f1W1, f1b1, W1sw, 144, 9, 0);
    cvt_swz<<<(192*5*64+255)/256, 256, 0, stream>>>(f1W2, f1b2, W2sw, 2784, 192, 1);

    conv_kernel<1><<<(E+31)/32, 256, 0, stream>>>(edge_emb, sh1buf, ei, node_s, nullptr,
                                                  W1sw, W2sw, s1, v1, E);
    fin1_kernel<<<((size_t)Nn*78 + 255)/256, 256, 0, stream>>>(node_s, deg, s1, v1, Nn);

    cvt_swz<<<(9*5*64+255)/256,   256, 0, stream>>>(f2W1, f2b1, W1sw, 144, 9, 0);
    cvt_swz<<<(242*5*64+255)/256, 256, 0, stream>>>(f2W2, f2b2, W2sw, 3464, 242, 2);

    conv_kernel<2><<<(E+31)/32, 256, 0, stream>>>(edge_emb, sh1buf, ei, s1, v1,
                                                  W1sw, W2sw, out, nullptr, E);
    fin2_kernel<<<((size_t)Nn*108 + 255)/256, 256, 0, stream>>>(s1, v1, deg, out, Nn);
}